// Round 11
// baseline (1496.787 us; speedup 1.0000x reference)
//
#include <hip/hip_runtime.h>

// Sinkhorn, multi-dispatch v2: ONE dispatch per iteration (54 total).
//   Col matvec (KT.w) is computed as per-block PARTIAL COLUMN SUMS by the
//   row-owning blocks (reusing the L2-hot K rows) accumulated via native
//   fp64 global atomics -> KT never materialized, traffic ~17MB/iter (was
//   33.5), dispatches 104 -> 54. Next dispatch reconstructs z elementwise
//   from the completed accumulator (no communication).
// Recurrence: V[0]=1, P[0]=1;
//   s: V[s+1]_i = INV_N/((M_s.V[s])_i + 2048*P[s]), M_s = K (s even)/KT (s odd)
//      P[s+1]  = INV_N/(sum(V[s]) + 2048*P[s])
// Dispatch t (0..49): z=V[2t] (reconstructed, ones at t=0), row MAC -> w=V[2t+1]
//   (stored to W), col partials -> ACC[(t+1)%3] (+= K_ij w_i), wsum atomic,
//   P_arr[t+1]=P[2t+1] stored. ACC 3-slot rotation: read t%3, acc (t+1)%3,
//   zero (t+2)%3 (cross-dispatch-boundary safe).
// Epilogue: w=W, wpad=P_arr[50]=P[99], z_j=INV_N/(ACC[2]_j+2048*P[99]),
//   zpad=INV_N/(wsum[50]+2048*P[99]).

#define INV_N (1.0 / 4096.0)

// ---- scratch layout inside d_out (67,108,864 bytes) ----
// K fp32 2048x2048 at 0 (out rows 0..1023; overwritten by k_out_top).
// High scratch (out rows 4090..4094; overwritten only by k_out_tail, last):
#define OFF_K 0UL
#define OFF_ACC (4090UL * 16384UL)        // ACC[0..2]: 3 x 2048 fp64 (rows 4090-4092)
#define OFF_W (4093UL * 16384UL)          // W: 2048 fp64 (row 4093)
#define OFF_P (4094UL * 16384UL)          // P_arr[0..50] fp64
#define OFF_WS (OFF_P + 512UL)            // wsum_arr[0..50] fp64

// fp64 exp (rel err ~3e-13 on [-20,0]).
static __device__ __forceinline__ double fexp(double x) {
  double t = x * 1.4426950408889634074;
  double n = rint(t);
  double r = fma(n, -0.69314718055994530942, x);
  double p = 2.7557319223985890653e-7;
  p = fma(p, r, 2.7557319223985890653e-6);
  p = fma(p, r, 2.4801587301587301587e-5);
  p = fma(p, r, 1.9841269841269841270e-4);
  p = fma(p, r, 1.3888888888888888889e-3);
  p = fma(p, r, 8.3333333333333333333e-3);
  p = fma(p, r, 4.1666666666666666667e-2);
  p = fma(p, r, 1.6666666666666666667e-1);
  p = fma(p, r, 0.5);
  p = fma(p, r, 1.0);
  p = fma(p, r, 1.0);
  long long bits = ((long long)(1023 + (int)n)) << 52;
  return p * __longlong_as_double(bits);
}

// Build K = exp(-20C) fp32 (grid-stride, no transpose) + zero ACC[1], wsum.
__global__ __launch_bounds__(256) void k_build(const float* __restrict__ C, char* base) {
  float* K = (float*)(base + OFF_K);
  int gid = blockIdx.x * 256 + threadIdx.x;  // 262144 threads, 4 float4 each
#pragma unroll
  for (int q = 0; q < 4; ++q) {
    int idx = gid + q * 262144;
    float4 c = ((const float4*)C)[idx];
    float4 f;
    f.x = (float)fexp(-20.0 * (double)c.x);
    f.y = (float)fexp(-20.0 * (double)c.y);
    f.z = (float)fexp(-20.0 * (double)c.z);
    f.w = (float)fexp(-20.0 * (double)c.w);
    ((float4*)K)[idx] = f;
  }
  if (blockIdx.x == 0) {
    double* A1 = (double*)(base + OFF_ACC) + 2048;  // ACC[1]: t=0's target
    for (int q = threadIdx.x; q < 2048; q += 256) A1[q] = 0.0;
    double* ws = (double*)(base + OFF_WS);
    if (threadIdx.x < 51) ws[threadIdx.x] = 0.0;
  }
}

// One iteration. 256 blocks x 512 thr (8 waves); wave wv owns row i=b*8+wv.
__global__ __launch_bounds__(512) void k_iter(char* base, int t) {
  const float* K = (const float*)(base + OFF_K);
  double* ACC = (double*)(base + OFF_ACC);
  double* W = (double*)(base + OFF_W);
  double* Pa = (double*)(base + OFF_P);
  double* WS = (double*)(base + OFF_WS);

  __shared__ double s_z[2048];
  __shared__ double s_w[8];

  const int tid = threadIdx.x, b = blockIdx.x;
  const int wv = tid >> 6, l = tid & 63;
  const int i = b * 8 + wv;

  // ---- phase 0: reconstruct z = V[2t] elementwise; pads ----
  double P0;  // P[2t]
  if (t == 0) {
    P0 = 1.0;
    s_z[tid] = 1.0; s_z[tid + 512] = 1.0; s_z[tid + 1024] = 1.0; s_z[tid + 1536] = 1.0;
  } else {
    const double Pm1 = Pa[t];                      // P[2t-1]
    P0 = INV_N / (WS[t] + 2048.0 * Pm1);           // P[2t]
    const double* Ain = ACC + (size_t)(t % 3) * 2048;
    const double c = 2048.0 * Pm1;
    s_z[tid] = INV_N / (Ain[tid] + c);
    s_z[tid + 512] = INV_N / (Ain[tid + 512] + c);
    s_z[tid + 1024] = INV_N / (Ain[tid + 1024] + c);
    s_z[tid + 1536] = INV_N / (Ain[tid + 1536] + c);
  }
  // zero next-next accumulator slot (nobody touches it this dispatch)
  if (tid < 8) (ACC + (size_t)((t + 2) % 3) * 2048)[b * 8 + tid] = 0.0;
  __syncthreads();

  // ---- phase 1: row MAC -> w_i; zsum folded in ----
  const float4* Kr = (const float4*)(K + (size_t)i * 2048);
  const double2* zr = (const double2*)s_z;
  double a0 = 0, a1 = 0, a2 = 0, a3 = 0, ts = 0;
#pragma unroll
  for (int k = 0; k < 8; ++k) {
    float4 m = Kr[l + 64 * k];
    double2 z0 = zr[2 * (l + 64 * k)];
    double2 z1 = zr[2 * (l + 64 * k) + 1];
    a0 = fma((double)m.x, z0.x, a0);
    a1 = fma((double)m.y, z0.y, a1);
    a2 = fma((double)m.z, z1.x, a2);
    a3 = fma((double)m.w, z1.y, a3);
    ts += (z0.x + z0.y) + (z1.x + z1.y);
  }
  double acc = (a0 + a1) + (a2 + a3);
#pragma unroll
  for (int off = 32; off; off >>= 1) {
    acc += __shfl_xor(acc, off, 64);
    ts += __shfl_xor(ts, off, 64);
  }
  double wi = INV_N / (acc + 2048.0 * P0);
  double P1 = INV_N / (ts + 2048.0 * P0);  // P[2t+1], identical in every wave/block
  if (l == 0) {
    s_w[wv] = wi;
    W[i] = wi;
  }
  if (b == 0 && tid == 0) Pa[t + 1] = P1;
  __syncthreads();

  // ---- phase 2: partial column sums of KT.w over this block's 8 rows ----
  // wave wv covers 256 j's (staggered start per block); K rows are L2-hot.
  double* Aout = ACC + (size_t)((t + 1) % 3) * 2048;
  const int jb = (((wv + b) & 7) << 8) + 4 * l;
  double p0 = 0, p1 = 0, p2 = 0, p3 = 0;
#pragma unroll
  for (int r = 0; r < 8; ++r) {
    float4 kv = *(const float4*)(K + (size_t)(b * 8 + r) * 2048 + jb);
    double wr = s_w[r];
    p0 = fma(wr, (double)kv.x, p0);
    p1 = fma(wr, (double)kv.y, p1);
    p2 = fma(wr, (double)kv.z, p2);
    p3 = fma(wr, (double)kv.w, p3);
  }
  unsafeAtomicAdd(Aout + jb + 0, p0);
  unsafeAtomicAdd(Aout + jb + 1, p1);
  unsafeAtomicAdd(Aout + jb + 2, p2);
  unsafeAtomicAdd(Aout + jb + 3, p3);
  if (tid == 0) {
    double s = ((s_w[0] + s_w[1]) + (s_w[2] + s_w[3])) + ((s_w[4] + s_w[5]) + (s_w[6] + s_w[7]));
    unsafeAtomicAdd(WS + t + 1, s);
  }
}

// Rows 0..2047: out_ij = 4096*min(w_i z_j exp(-20C_ij),1); right half const.
__global__ __launch_bounds__(512) void k_out_top(const float* __restrict__ C, char* base) {
  const double* A2 = (const double*)(base + OFF_ACC) + 2 * 2048;  // ACC[50%3=2]
  const double* W = (const double*)(base + OFF_W);
  const double* Pa = (const double*)(base + OFF_P);
  const double* WS = (const double*)(base + OFF_WS);
  float* out = (float*)base;
  __shared__ double s_z[2048];
  __shared__ double s_w8[8];
  int tid = threadIdx.x, b = blockIdx.x;
  double wpad = Pa[50];                         // P[99]
  double zpad = INV_N / (WS[50] + 2048.0 * wpad);  // P[100]
  const double c = 2048.0 * wpad;
  s_z[tid] = INV_N / (A2[tid] + c);
  s_z[tid + 512] = INV_N / (A2[tid + 512] + c);
  s_z[tid + 1024] = INV_N / (A2[tid + 1024] + c);
  s_z[tid + 1536] = INV_N / (A2[tid + 1536] + c);
  if (tid < 8) s_w8[tid] = W[b * 8 + tid];
  __syncthreads();
  int wv = tid >> 6, l = tid & 63;
  int i = b * 8 + wv;
  double wi = s_w8[wv];
  const float4* Cr = (const float4*)(C + (size_t)i * 2048);
  const double2* zr = (const double2*)s_z;
  float* orow = out + (size_t)i * 4096;
#pragma unroll 2
  for (int k = 0; k < 8; ++k) {
    float4 cv = Cr[l + 64 * k];
    double2 z0 = zr[2 * (l + 64 * k)];
    double2 z1 = zr[2 * (l + 64 * k) + 1];
    float4 f;
    f.x = (float)(4096.0 * fmin(wi * z0.x * fexp(-20.0 * (double)cv.x), 1.0));
    f.y = (float)(4096.0 * fmin(wi * z0.y * fexp(-20.0 * (double)cv.y), 1.0));
    f.z = (float)(4096.0 * fmin(wi * z1.x * fexp(-20.0 * (double)cv.z), 1.0));
    f.w = (float)(4096.0 * fmin(wi * z1.y * fexp(-20.0 * (double)cv.w), 1.0));
    ((float4*)orow)[l + 64 * k] = f;
  }
  float cr = (float)(4096.0 * fmin(wi * zpad, 1.0));
  float4 fct; fct.x = cr; fct.y = cr; fct.z = cr; fct.w = cr;
#pragma unroll
  for (int k = 0; k < 8; ++k) ((float4*)(orow + 2048))[l + 64 * k] = fct;
}

// Rows 2048..4089 (identical): left 4096*min(wpad*z_j,1), right const.
__global__ __launch_bounds__(512) void k_out_bot(char* base) {
  const double* A2 = (const double*)(base + OFF_ACC) + 2 * 2048;
  const double* Pa = (const double*)(base + OFF_P);
  const double* WS = (const double*)(base + OFF_WS);
  float* out = (float*)base;
  __shared__ float s_val[2048];
  int tid = threadIdx.x, b = blockIdx.x;
  double wpad = Pa[50];
  double zpad = INV_N / (WS[50] + 2048.0 * wpad);
  const double c = 2048.0 * wpad;
  s_val[tid] = (float)(4096.0 * fmin(wpad * (INV_N / (A2[tid] + c)), 1.0));
  s_val[tid + 512] = (float)(4096.0 * fmin(wpad * (INV_N / (A2[tid + 512] + c)), 1.0));
  s_val[tid + 1024] = (float)(4096.0 * fmin(wpad * (INV_N / (A2[tid + 1024] + c)), 1.0));
  s_val[tid + 1536] = (float)(4096.0 * fmin(wpad * (INV_N / (A2[tid + 1536] + c)), 1.0));
  float cf = (float)(4096.0 * fmin(wpad * zpad, 1.0));
  __syncthreads();
  int wv = tid >> 6, l = tid & 63;
  int row = 2048 + b * 8 + wv;
  if (row <= 4089) {
    float* orow = out + (size_t)row * 4096;
    float4 fc; fc.x = cf; fc.y = cf; fc.z = cf; fc.w = cf;
#pragma unroll
    for (int k = 0; k < 8; ++k) ((float4*)orow)[l + 64 * k] = ((const float4*)s_val)[l + 64 * k];
#pragma unroll
    for (int k = 0; k < 8; ++k) ((float4*)(orow + 2048))[l + 64 * k] = fc;
  }
}

// Rows 4090..4095 (overwrites scratch; single block, staged first).
__global__ __launch_bounds__(512) void k_out_tail(char* base) {
  const double* A2 = (const double*)(base + OFF_ACC) + 2 * 2048;
  const double* Pa = (const double*)(base + OFF_P);
  const double* WS = (const double*)(base + OFF_WS);
  float* out = (float*)base;
  __shared__ float s_val[2048];
  int tid = threadIdx.x;
  double wpad = Pa[50];
  double zpad = INV_N / (WS[50] + 2048.0 * wpad);
  const double c = 2048.0 * wpad;
  s_val[tid] = (float)(4096.0 * fmin(wpad * (INV_N / (A2[tid] + c)), 1.0));
  s_val[tid + 512] = (float)(4096.0 * fmin(wpad * (INV_N / (A2[tid + 512] + c)), 1.0));
  s_val[tid + 1024] = (float)(4096.0 * fmin(wpad * (INV_N / (A2[tid + 1024] + c)), 1.0));
  s_val[tid + 1536] = (float)(4096.0 * fmin(wpad * (INV_N / (A2[tid + 1536] + c)), 1.0));
  float cf = (float)(4096.0 * fmin(wpad * zpad, 1.0));
  __syncthreads();  // all scratch reads complete before overwriting below
  float4 fc; fc.x = cf; fc.y = cf; fc.z = cf; fc.w = cf;
  for (int row = 4090; row <= 4095; ++row) {
    float4* orow = (float4*)(out + (size_t)row * 4096);
    for (int q = tid; q < 1024; q += 512)
      orow[q] = (q < 512) ? ((const float4*)s_val)[q] : fc;
  }
}

extern "C" void kernel_launch(void* const* d_in, const int* in_sizes, int n_in,
                              void* d_out, int out_size, void* d_ws, size_t ws_size,
                              hipStream_t stream) {
  (void)in_sizes; (void)n_in; (void)out_size; (void)d_ws; (void)ws_size;
  const float* C = (const float*)d_in[0];
  char* base = (char*)d_out;
  k_build<<<1024, 256, 0, stream>>>(C, base);
  for (int t = 0; t < 50; ++t) k_iter<<<256, 512, 0, stream>>>(base, t);
  k_out_top<<<256, 512, 0, stream>>>(C, base);
  k_out_bot<<<256, 512, 0, stream>>>(base);
  k_out_tail<<<1, 512, 0, stream>>>(base);
}